// Round 3
// baseline (281.477 us; speedup 1.0000x reference)
//
#include <hip/hip_runtime.h>
#include <cstdint>
#include <cstddef>

#define D_DIM   256
#define B_ROWS  1024
#define C_CLS   200000
#define S_SC    64.0f
#define COS_M_F 0.87758256189037271612f
#define SIN_M_F 0.47942553860420300027f
#define EPS_F   1e-8f

#define BN 128
#define BM 256
#define BK 64
#define NPAN 1563   /* ceil(200000/128); covers 200064 cols */

typedef short bf16x8 __attribute__((ext_vector_type(8)));
typedef float f32x4  __attribute__((ext_vector_type(4)));

__device__ __forceinline__ unsigned short f2bf(float x) {
  unsigned int u = __builtin_bit_cast(unsigned int, x);
  return (unsigned short)((u + 0x8000u) >> 16);
}
__device__ __forceinline__ float bf2f(unsigned short u) {
  return __builtin_bit_cast(float, ((unsigned int)u) << 16);
}

// ---------------- kernel 1: normalize embeddings -> bf16 in ws ----------------
__global__ void k_norm_embed(const float* __restrict__ emb,
                             unsigned short* __restrict__ ebf) {
  int wid = threadIdx.x >> 6, lane = threadIdx.x & 63;
  int row = (blockIdx.x << 2) + wid;
  const float4 v = *reinterpret_cast<const float4*>(emb + (size_t)row * D_DIM + lane * 4);
  float ss = v.x * v.x + v.y * v.y + v.z * v.z + v.w * v.w;
#pragma unroll
  for (int m = 32; m >= 1; m >>= 1) ss += __shfl_xor(ss, m, 64);
  float inv = 1.0f / fmaxf(sqrtf(ss), 1e-12f);
  ushort4 o;
  o.x = f2bf(v.x * inv); o.y = f2bf(v.y * inv);
  o.z = f2bf(v.z * inv); o.w = f2bf(v.w * inv);
  *reinterpret_cast<ushort4*>(ebf + (size_t)row * D_DIM + lane * 4) = o;
}

// ---------------- kernel 2: panel-persistent GEMM + exp + row-sum -------------
// One block per N-panel of 128 prototypes. B (normalized bf16) lives in LDS for
// the whole block; loop over 4 M-tiles of 256 rows; only A is staged per K-step.
__global__ __launch_bounds__(512, 2) void k_gemm_panel(
    const unsigned short* __restrict__ ebf, const float* __restrict__ proto,
    float* __restrict__ sums) {
  __shared__ __align__(16) short Bs[BN * D_DIM];   // 64 KiB, row=512B=32 slots
  __shared__ __align__(16) short As[2][BM * BK];   // 2 x 32 KiB, row=128B=8 slots
  __shared__ float rowsum[BM];

  const int t = threadIdx.x;
  const int lane = t & 63;
  const int wm = (t >> 6) >> 1;      // 0..3
  const int wn = (t >> 6) & 1;       // 0..1
  const int n0 = (int)blockIdx.x * BN;

  // ---------------- prologue: B panel load + normalize + cvt -> LDS ----------
  {
    const int brow = t >> 2;              // 0..127
    const int kq = (t & 3) * 64;          // K chunk start
    int c = n0 + brow; if (c >= C_CLS) c = C_CLS - 1;   // clamp; masked in epilogue
    const float* bp = proto + (size_t)c * D_DIM + kq;
    float4 bv[16];
#pragma unroll
    for (int i = 0; i < 16; ++i) bv[i] = reinterpret_cast<const float4*>(bp)[i];

    // stage A slice for step 0 (mt=0,kk=0) while B loads are in flight
#pragma unroll
    for (int j = 0; j < 4; ++j) {
      int row = j * 64 + (t >> 3);
      int sl = (t & 7) ^ (row & 7);
      const unsigned short* g = ebf + (size_t)row * D_DIM + sl * 8;
      __builtin_amdgcn_global_load_lds(
          (const __attribute__((address_space(1))) unsigned int*)(const void*)g,
          (__attribute__((address_space(3))) unsigned int*)(void*)(&As[0][0] + j * 4096 + t * 8),
          16, 0, 0);
    }

    float ss = 0.0f;
#pragma unroll
    for (int i = 0; i < 16; ++i)
      ss += bv[i].x * bv[i].x + bv[i].y * bv[i].y + bv[i].z * bv[i].z + bv[i].w * bv[i].w;
    // 4 threads (t&3 = 0..3) share one row -> reduce across lanes l^1, l^2
    ss += __shfl_xor(ss, 1, 64);
    ss += __shfl_xor(ss, 2, 64);
    float inv = 1.0f / fmaxf(sqrtf(ss), 1e-12f);
#pragma unroll
    for (int j = 0; j < 8; ++j) {
      float4 a = bv[2 * j], b = bv[2 * j + 1];
      bf16x8 w;
      w[0] = (short)f2bf(a.x * inv); w[1] = (short)f2bf(a.y * inv);
      w[2] = (short)f2bf(a.z * inv); w[3] = (short)f2bf(a.w * inv);
      w[4] = (short)f2bf(b.x * inv); w[5] = (short)f2bf(b.y * inv);
      w[6] = (short)f2bf(b.z * inv); w[7] = (short)f2bf(b.w * inv);
      int slot = (kq >> 3) + j;                 // logical 16B slot (0..31)
      int phys = slot ^ (brow & 7);             // XOR swizzle
      *reinterpret_cast<bf16x8*>(&Bs[brow * D_DIM + phys * 8]) = w;
    }
  }
  if (t < BM) rowsum[t] = 0.0f;
  asm volatile("s_waitcnt vmcnt(0)" ::: "memory");
  __syncthreads();

  // ---------------- main loop: 16 steps = 4 M-tiles x 4 K-steps --------------
  f32x4 acc[4][4];
  const f32x4 fz = {0.0f, 0.0f, 0.0f, 0.0f};
#pragma unroll
  for (int mi = 0; mi < 4; ++mi)
#pragma unroll
    for (int ni = 0; ni < 4; ++ni) acc[mi][ni] = fz;

  int cur = 0;
#pragma unroll 1
  for (int step = 0; step < 16; ++step) {
    const int mt = step >> 2, kk = step & 3;

    // prefetch next A slice into the other buffer
    if (step < 15) {
      const int sn = step + 1;
      const int m0n = (sn >> 2) * BM, k0n = (sn & 3) * BK;
      short* dst = &As[cur ^ 1][0];
#pragma unroll
      for (int j = 0; j < 4; ++j) {
        int row = j * 64 + (t >> 3);
        int sl = (t & 7) ^ (row & 7);
        const unsigned short* g = ebf + (size_t)(m0n + row) * D_DIM + k0n + sl * 8;
        __builtin_amdgcn_global_load_lds(
            (const __attribute__((address_space(1))) unsigned int*)(const void*)g,
            (__attribute__((address_space(3))) unsigned int*)(void*)(dst + j * 4096 + t * 8),
            16, 0, 0);
      }
    }

#pragma unroll
    for (int ks = 0; ks < 2; ++ks) {
      bf16x8 af[4], bfv[4];
#pragma unroll
      for (int mi = 0; mi < 4; ++mi) {
        int r = wm * 64 + mi * 16 + (lane & 15);
        int sl = (ks * 4 + (lane >> 4)) ^ (r & 7);
        af[mi] = *reinterpret_cast<const bf16x8*>(&As[cur][r * BK + sl * 8]);
      }
#pragma unroll
      for (int ni = 0; ni < 4; ++ni) {
        int rb = wn * 64 + ni * 16 + (lane & 15);
        int slot = kk * 8 + ks * 4 + (lane >> 4);
        int phys = slot ^ (rb & 7);
        bfv[ni] = *reinterpret_cast<const bf16x8*>(&Bs[rb * D_DIM + phys * 8]);
      }
      __builtin_amdgcn_s_setprio(1);
#pragma unroll
      for (int mi = 0; mi < 4; ++mi)
#pragma unroll
        for (int ni = 0; ni < 4; ++ni)
          acc[mi][ni] = __builtin_amdgcn_mfma_f32_16x16x32_bf16(
              af[mi], bfv[ni], acc[mi][ni], 0, 0, 0);
      __builtin_amdgcn_s_setprio(0);
    }

    if (kk == 3) {
      // epilogue for this M-tile: exp -> per-row partial sums in LDS
      float vmask[4];
      const int ccol = n0 + wn * 64 + (lane & 15);
#pragma unroll
      for (int ni = 0; ni < 4; ++ni)
        vmask[ni] = (ccol + ni * 16 < C_CLS) ? 1.0f : 0.0f;
#pragma unroll
      for (int mi = 0; mi < 4; ++mi) {
#pragma unroll
        for (int j = 0; j < 4; ++j) {
          float rs = 0.0f;
#pragma unroll
          for (int ni = 0; ni < 4; ++ni)
            rs += vmask[ni] * __expf(S_SC * acc[mi][ni][j]);
          rs += __shfl_xor(rs, 1, 64);
          rs += __shfl_xor(rs, 2, 64);
          rs += __shfl_xor(rs, 4, 64);
          rs += __shfl_xor(rs, 8, 64);
          if ((lane & 15) == 0)
            atomicAdd(&rowsum[wm * 64 + mi * 16 + ((lane >> 4) << 2) + j], rs);
        }
      }
#pragma unroll
      for (int mi = 0; mi < 4; ++mi)
#pragma unroll
        for (int ni = 0; ni < 4; ++ni) acc[mi][ni] = fz;
    }

    asm volatile("s_waitcnt vmcnt(0)" ::: "memory");
    __syncthreads();

    if (kk == 3 && t < BM) {
      atomicAdd(&sums[mt * BM + t], rowsum[t]);
      rowsum[t] = 0.0f;   // next epilogue is >=4 barriers away: safe
    }
    cur ^= 1;
  }
}

// ---------------- kernel 3: label column + final loss -------------------------
__global__ void k_finalize(const unsigned short* __restrict__ ebf,
                           const float* __restrict__ proto,
                           const int* __restrict__ labels,
                           const float* __restrict__ sums,
                           float* __restrict__ out) {
  __shared__ float part[4];
  int wid = threadIdx.x >> 6, lane = threadIdx.x & 63;
  int b = (blockIdx.x << 2) + wid;
  int lab = labels[b];
  const float4 pv = reinterpret_cast<const float4*>(proto + (size_t)lab * D_DIM)[lane];
  float ss = pv.x * pv.x + pv.y * pv.y + pv.z * pv.z + pv.w * pv.w;
#pragma unroll
  for (int m = 32; m >= 1; m >>= 1) ss += __shfl_xor(ss, m, 64);
  float inv = 1.0f / fmaxf(sqrtf(ss), 1e-12f);
  const unsigned short* e = ebf + (size_t)b * D_DIM + lane * 4;
  float dot = bf2f(e[0]) * bf2f(f2bf(pv.x * inv))
            + bf2f(e[1]) * bf2f(f2bf(pv.y * inv))
            + bf2f(e[2]) * bf2f(f2bf(pv.z * inv))
            + bf2f(e[3]) * bf2f(f2bf(pv.w * inv));
#pragma unroll
  for (int m = 32; m >= 1; m >>= 1) dot += __shfl_xor(dot, m, 64);
  if (lane == 0) {
    float cs = dot;
    float sn = sqrtf(fmaxf(1.0f - cs * cs, EPS_F));
    sn = fminf(fmaxf(sn, EPS_F), 1.0f - EPS_F);
    float phi = cs * COS_M_F - sn * SIN_M_F;
    float sp = S_SC * phi;
    float total = sums[b] - __expf(S_SC * cs) + __expf(sp);
    part[wid] = logf(total) - sp;
  }
  __syncthreads();
  if (threadIdx.x == 0) {
    float s = part[0] + part[1] + part[2] + part[3];
    atomicAdd(out, s * (1.0f / (float)B_ROWS));
  }
}

// ---------------- launcher ----------------------------------------------------
extern "C" void kernel_launch(void* const* d_in, const int* in_sizes, int n_in,
                              void* d_out, int out_size, void* d_ws, size_t ws_size,
                              hipStream_t stream) {
  const float* emb    = (const float*)d_in[0];
  const int*   labels = (const int*)d_in[1];
  const float* proto  = (const float*)d_in[2];
  float* out = (float*)d_out;

  char* ws = (char*)d_ws;
  unsigned short* ebf = (unsigned short*)ws;        // 1024*256*2 = 524288 B
  float* sums = (float*)(ws + 524288);              // 1024*4 B

  hipMemsetAsync(sums, 0, B_ROWS * sizeof(float), stream);
  hipMemsetAsync(out, 0, sizeof(float), stream);

  k_norm_embed<<<B_ROWS / 4, 256, 0, stream>>>(emb, ebf);
  k_gemm_panel<<<NPAN, 512, 0, stream>>>(ebf, proto, sums);
  k_finalize<<<B_ROWS / 4, 256, 0, stream>>>(ebf, proto, labels, sums, out);
}

// Round 4
// 211.148 us; speedup vs baseline: 1.3331x; 1.3331x over previous
//
#include <hip/hip_runtime.h>
#include <cstdint>
#include <cstddef>

#define D_DIM   256
#define B_ROWS  1024
#define C_CLS   200000
#define S_SC    64.0f
#define COS_M_F 0.87758256189037271612f
#define SIN_M_F 0.47942553860420300027f
#define EPS_F   1e-8f

#define BM 256
#define BN 256
#define NTN 782                    /* N-tiles: 782*256 = 200192 */
#define CPAD (NTN * BN)            /* 200192 */
#define NBLK (4 * NTN)             /* 3128 = 8*391 */

typedef short bf16x8 __attribute__((ext_vector_type(8)));
typedef float f32x4  __attribute__((ext_vector_type(4)));

__device__ __forceinline__ unsigned short f2bf(float x) {
  unsigned int u = __builtin_bit_cast(unsigned int, x);
  return (unsigned short)((u + 0x8000u) >> 16);
}
__device__ __forceinline__ float bf2f(unsigned short u) {
  return __builtin_bit_cast(float, ((unsigned int)u) << 16);
}

// ---------------- kernel 1: normalize embeddings -> bf16 in ws ----------------
__global__ void k_norm_embed(const float* __restrict__ emb,
                             unsigned short* __restrict__ ebf) {
  int wid = threadIdx.x >> 6, lane = threadIdx.x & 63;
  int row = (blockIdx.x << 2) + wid;
  const float4 v = *reinterpret_cast<const float4*>(emb + (size_t)row * D_DIM + lane * 4);
  float ss = v.x * v.x + v.y * v.y + v.z * v.z + v.w * v.w;
#pragma unroll
  for (int m = 32; m >= 1; m >>= 1) ss += __shfl_xor(ss, m, 64);
  float inv = 1.0f / fmaxf(sqrtf(ss), 1e-12f);
  ushort4 o;
  o.x = f2bf(v.x * inv); o.y = f2bf(v.y * inv);
  o.z = f2bf(v.z * inv); o.w = f2bf(v.w * inv);
  *reinterpret_cast<ushort4*>(ebf + (size_t)row * D_DIM + lane * 4) = o;
}

// ---------------- kernel 2: normalize prototypes -> bf16, zero-pad ------------
__global__ void k_proto_norm_cvt(const float* __restrict__ proto,
                                 unsigned short* __restrict__ pbf) {
  int wid = threadIdx.x >> 6, lane = threadIdx.x & 63;
  int row = (blockIdx.x << 2) + wid;               // grid = CPAD/4
  if (row >= C_CLS) {
    *reinterpret_cast<ushort4*>(pbf + (size_t)row * D_DIM + lane * 4) =
        (ushort4){0, 0, 0, 0};
    return;
  }
  const float4 v = *reinterpret_cast<const float4*>(proto + (size_t)row * D_DIM + lane * 4);
  float ss = v.x * v.x + v.y * v.y + v.z * v.z + v.w * v.w;
#pragma unroll
  for (int m = 32; m >= 1; m >>= 1) ss += __shfl_xor(ss, m, 64);
  float inv = 1.0f / fmaxf(sqrtf(ss), 1e-12f);
  ushort4 o;
  o.x = f2bf(v.x * inv); o.y = f2bf(v.y * inv);
  o.z = f2bf(v.z * inv); o.w = f2bf(v.w * inv);
  *reinterpret_cast<ushort4*>(pbf + (size_t)row * D_DIM + lane * 4) = o;
}

// ---------------- kernel 3: double-buffered fused GEMM + exp + row-sum --------
// 256x256 tile, K fully unrolled into 4 chunks of 64, 2 LDS buffers.
// Schedule: S0,S1 | C0 | S2 under C1 | S3 under C2 | C3 | epilogue.
__global__ __launch_bounds__(512, 2) void k_gemm_db(
    const unsigned short* __restrict__ ebf, const unsigned short* __restrict__ pbf,
    float* __restrict__ sums) {
  // [buf][operand A=0/B=1][256 rows * 64 shorts]; row = 128 B, XOR-swizzled slots
  __shared__ __align__(16) short Ls[2][2][BM * 64];   // 128 KiB
  __shared__ float rowsum[BM];

  const int t = threadIdx.x;
  const int lane = t & 63;
  const int wm = (t >> 6) >> 1;     // 0..3  (M wave index, 64 rows each)
  const int wn = (t >> 6) & 1;      // 0..1  (N wave index, 128 cols each)

  int bid = (int)blockIdx.x;
  int w = (bid & 7) * (NBLK / 8) + (bid >> 3);   // bijective XCD swizzle
  const int ntile = w >> 2;
  const int mtile = w & 3;
  const int m0 = mtile * BM;
  const int n0 = ntile * BN;

  if (t < BM) rowsum[t] = 0.0f;

  f32x4 acc[4][8];
  const f32x4 fz = {0.0f, 0.0f, 0.0f, 0.0f};
#pragma unroll
  for (int mi = 0; mi < 4; ++mi)
#pragma unroll
    for (int ni = 0; ni < 8; ++ni) acc[mi][ni] = fz;

  auto STAGE = [&](int bb, int ck) {
    const int k0 = ck * 64;
    short* dstA = &Ls[bb][0][0];
    short* dstB = &Ls[bb][1][0];
#pragma unroll
    for (int j = 0; j < 4; ++j) {
      int row = j * 64 + (t >> 3);
      int sl = (t & 7) ^ (row & 7);
      const unsigned short* gA = ebf + (size_t)(m0 + row) * D_DIM + k0 + sl * 8;
      __builtin_amdgcn_global_load_lds(
          (const __attribute__((address_space(1))) unsigned int*)(const void*)gA,
          (__attribute__((address_space(3))) unsigned int*)(void*)(dstA + j * 4096 + t * 8),
          16, 0, 0);
      const unsigned short* gB = pbf + (size_t)(n0 + row) * D_DIM + k0 + sl * 8;
      __builtin_amdgcn_global_load_lds(
          (const __attribute__((address_space(1))) unsigned int*)(const void*)gB,
          (__attribute__((address_space(3))) unsigned int*)(void*)(dstB + j * 4096 + t * 8),
          16, 0, 0);
    }
  };

  auto COMPUTE = [&](int bb) {
#pragma unroll
    for (int ks = 0; ks < 2; ++ks) {
      bf16x8 af[4];
#pragma unroll
      for (int mi = 0; mi < 4; ++mi) {
        int r = wm * 64 + mi * 16 + (lane & 15);
        int sl = (ks * 4 + (lane >> 4)) ^ (r & 7);
        af[mi] = *reinterpret_cast<const bf16x8*>(&Ls[bb][0][r * 64 + sl * 8]);
      }
      __builtin_amdgcn_s_setprio(1);
#pragma unroll
      for (int ni = 0; ni < 8; ++ni) {
        int r = wn * 128 + ni * 16 + (lane & 15);
        int sl = (ks * 4 + (lane >> 4)) ^ (r & 7);
        bf16x8 bv = *reinterpret_cast<const bf16x8*>(&Ls[bb][1][r * 64 + sl * 8]);
#pragma unroll
        for (int mi = 0; mi < 4; ++mi)
          acc[mi][ni] = __builtin_amdgcn_mfma_f32_16x16x32_bf16(
              af[mi], bv, acc[mi][ni], 0, 0, 0);
      }
      __builtin_amdgcn_s_setprio(0);
    }
  };

  // ---- fully unrolled double-buffered schedule ----
  STAGE(0, 0);
  STAGE(1, 1);
  __syncthreads();      // drains c0+c1 (prologue; only exposed wait)
  COMPUTE(0);
  __syncthreads();      // release b0 (cheap: c-loads long done)
  STAGE(0, 2);          // c2 flies under C1
  COMPUTE(1);
  __syncthreads();      // drains c2 -> b0 ready; release b1
  STAGE(1, 3);          // c3 flies under C2
  COMPUTE(0);
  __syncthreads();      // drains c3 -> b1 ready
  COMPUTE(1);

  // ---- epilogue: exp -> per-row sums ----
  // elem (mi,ni,j): row = wm*64+mi*16+(lane>>4)*4+j ; col = n0+wn*128+ni*16+(lane&15)
  float vmask[8];
  const int ccol = n0 + wn * 128 + (lane & 15);
#pragma unroll
  for (int ni = 0; ni < 8; ++ni) vmask[ni] = (ccol + ni * 16 < C_CLS) ? 1.0f : 0.0f;
#pragma unroll
  for (int mi = 0; mi < 4; ++mi) {
#pragma unroll
    for (int j = 0; j < 4; ++j) {
      float rs = 0.0f;
#pragma unroll
      for (int ni = 0; ni < 8; ++ni)
        rs += vmask[ni] * __expf(S_SC * acc[mi][ni][j]);
      rs += __shfl_xor(rs, 1, 64);
      rs += __shfl_xor(rs, 2, 64);
      rs += __shfl_xor(rs, 4, 64);
      rs += __shfl_xor(rs, 8, 64);
      if ((lane & 15) == 0)
        atomicAdd(&rowsum[wm * 64 + mi * 16 + ((lane >> 4) << 2) + j], rs);
    }
  }
  __syncthreads();
  if (t < BM) atomicAdd(&sums[m0 + t], rowsum[t]);
}

// ---------------- kernel 4: label column + final loss -------------------------
__global__ void k_finalize(const unsigned short* __restrict__ ebf,
                           const unsigned short* __restrict__ pbf,
                           const int* __restrict__ labels,
                           const float* __restrict__ sums,
                           float* __restrict__ out) {
  __shared__ float part[4];
  int wid = threadIdx.x >> 6, lane = threadIdx.x & 63;
  int b = (blockIdx.x << 2) + wid;
  int lab = labels[b];
  const unsigned short* e = ebf + (size_t)b * D_DIM;
  const unsigned short* p = pbf + (size_t)lab * D_DIM;
  float dot = 0.0f;
#pragma unroll
  for (int i = 0; i < 4; ++i) {
    int d = lane * 4 + i;
    dot += bf2f(e[d]) * bf2f(p[d]);
  }
#pragma unroll
  for (int m = 32; m >= 1; m >>= 1) dot += __shfl_xor(dot, m, 64);
  if (lane == 0) {
    float cs = dot;
    float sn = sqrtf(fmaxf(1.0f - cs * cs, EPS_F));
    sn = fminf(fmaxf(sn, EPS_F), 1.0f - EPS_F);
    float phi = cs * COS_M_F - sn * SIN_M_F;
    float sp = S_SC * phi;
    float total = sums[b] - __expf(S_SC * cs) + __expf(sp);
    part[wid] = logf(total) - sp;
  }
  __syncthreads();
  if (threadIdx.x == 0) {
    float s = part[0] + part[1] + part[2] + part[3];
    atomicAdd(out, s * (1.0f / (float)B_ROWS));
  }
}

// ---------------- launcher ----------------------------------------------------
extern "C" void kernel_launch(void* const* d_in, const int* in_sizes, int n_in,
                              void* d_out, int out_size, void* d_ws, size_t ws_size,
                              hipStream_t stream) {
  const float* emb    = (const float*)d_in[0];
  const int*   labels = (const int*)d_in[1];
  const float* proto  = (const float*)d_in[2];
  float* out = (float*)d_out;

  char* ws = (char*)d_ws;
  unsigned short* ebf = (unsigned short*)ws;                 // 524288 B
  float* sums = (float*)(ws + 524288);                       // 4096 B
  unsigned short* pbf = (unsigned short*)(ws + 2097152);     // CPAD*256*2 = 102.5 MB

  hipMemsetAsync(sums, 0, B_ROWS * sizeof(float), stream);
  hipMemsetAsync(out, 0, sizeof(float), stream);

  k_norm_embed<<<B_ROWS / 4, 256, 0, stream>>>(emb, ebf);
  k_proto_norm_cvt<<<CPAD / 4, 256, 0, stream>>>(proto, pbf);
  k_gemm_db<<<NBLK, 512, 0, stream>>>(ebf, pbf, sums);
  k_finalize<<<B_ROWS / 4, 256, 0, stream>>>(ebf, pbf, labels, sums, out);
}